// Round 9
// baseline (288.964 us; speedup 1.0000x reference)
//
#include <hip/hip_runtime.h>
#include <hip/hip_fp16.h>

#define LRELU(v) ((v) > 0.f ? (v) : 0.2f * (v))

typedef _Float16 f16x8 __attribute__((ext_vector_type(8)));
typedef float f32x4 __attribute__((ext_vector_type(4)));

__device__ __forceinline__ f16x8 f16x8_zero() {
    f16x8 v;
#pragma unroll
    for (int j = 0; j < 8; ++j) v[j] = (_Float16)0.f;
    return v;
}

// ---------------- CSR construction ----------------
__global__ __launch_bounds__(256) void hist_kernel(const int* __restrict__ dst,
                                                   int* __restrict__ cnt, int E) {
    int e = blockIdx.x * 256 + threadIdx.x;
    if (e < E) atomicAdd(&cnt[dst[e]], 1);
}

__global__ __launch_bounds__(256) void scan_blk(const int* __restrict__ cnt,
                                                int* __restrict__ offv,
                                                int* __restrict__ bsum, int N) {
    __shared__ int sh[256];
    const int t = threadIdx.x;
    const int base = blockIdx.x * 1024 + t * 4;
    int v0 = (base + 0 < N) ? cnt[base + 0] : 0;
    int v1 = (base + 1 < N) ? cnt[base + 1] : 0;
    int v2 = (base + 2 < N) ? cnt[base + 2] : 0;
    int v3 = (base + 3 < N) ? cnt[base + 3] : 0;
    const int T = v0 + v1 + v2 + v3;
    sh[t] = T;
    __syncthreads();
    for (int o = 1; o < 256; o <<= 1) {
        int x = (t >= o) ? sh[t - o] : 0;
        __syncthreads();
        sh[t] += x;
        __syncthreads();
    }
    const int excl = sh[t] - T;
    if (t == 255) bsum[blockIdx.x] = sh[255];
    if (base + 0 < N) offv[base + 0] = excl;
    if (base + 1 < N) offv[base + 1] = excl + v0;
    if (base + 2 < N) offv[base + 2] = excl + v0 + v1;
    if (base + 3 < N) offv[base + 3] = excl + v0 + v1 + v2;
}

__global__ __launch_bounds__(64) void scan_top(int* __restrict__ bsum,
                                               int* __restrict__ offv,
                                               int NB, int N) {
    const int t = threadIdx.x;
    const int v = (t < NB) ? bsum[t] : 0;
    int incl = v;
#pragma unroll
    for (int o = 1; o < 64; o <<= 1) {
        int x = __shfl_up(incl, o);
        if (t >= o) incl += x;
    }
    if (t < NB) bsum[t] = incl - v;
    if (t == NB - 1) offv[N] = incl;
}

__global__ __launch_bounds__(256) void scan_add(int* __restrict__ offv,
                                                const int* __restrict__ bsum, int N) {
    const int base = blockIdx.x * 1024 + threadIdx.x * 4;
    const int add = bsum[blockIdx.x];
#pragma unroll
    for (int i = 0; i < 4; ++i)
        if (base + i < N) offv[base + i] += add;
}

__global__ __launch_bounds__(256) void fill_kernel(const int* __restrict__ dst,
                                                   const int* __restrict__ srcv,
                                                   const int* __restrict__ offv,
                                                   int* __restrict__ cur,
                                                   int* __restrict__ csrsrc, int E) {
    int e = blockIdx.x * 256 + threadIdx.x;
    if (e < E) {
        int d = dst[e];
        int p = atomicAdd(&cur[d], 1);
        csrsrc[offv[d] + p] = srcv[e];
    }
}

// ---------------- weight prep: transpose f32 [K][Nn] -> f16 [Nn][K] ----------------
__global__ __launch_bounds__(256) void prep_w16(const float* __restrict__ W,
                                                _Float16* __restrict__ wt,
                                                int K, int Nn) {
    int idx = blockIdx.x * 256 + threadIdx.x;
    if (idx < K * Nn) {
        int k = idx / Nn, nn2 = idx - k * Nn;
        wt[(size_t)nn2 * K + k] = (_Float16)W[idx];
    }
}

// ---------------- f32 -> f16 convert (x input) ----------------
__global__ __launch_bounds__(256) void cvt_f16(const float* __restrict__ in,
                                               _Float16* __restrict__ out, int n4) {
    int i = blockIdx.x * 256 + threadIdx.x;
    if (i < n4) {
        float4 v = *(const float4*)(in + (size_t)i * 4);
        _Float16 o[4] = {(_Float16)v.x, (_Float16)v.y, (_Float16)v.z, (_Float16)v.w};
        *(float2*)(out + (size_t)i * 4) = *(float2*)o;
    }
}

// ---------------- f16 MFMA GEMM, LDS-staged A, fused alpha + f16 h out ----------
template <int WM, int WN, int K, int H>
__global__ __launch_bounds__(WM * WN * 64) void gemm_f16_fused(
    const _Float16* __restrict__ A, const _Float16* __restrict__ Wt,
    const float* __restrict__ a_s, const float* __restrict__ a_d,
    _Float16* __restrict__ hout, float* __restrict__ als,
    float* __restrict__ ald, int M, int Nn) {
    constexpr int BM = WM * 64;
    constexpr int T = WM * WN * 64;
    constexpr int CHUNKS = BM * 16;
    __shared__ f16x8 Atile[BM * 16];
    const int t = threadIdx.x;
    const int lane = t & 63;
    const int wv = t >> 6;
    const int wm = wv / WN, wn = wv % WN;
    const int m0 = blockIdx.x * BM;
    const int n0 = blockIdx.y * (WN * 64);
    const int l15 = lane & 15, lg = lane >> 4;

    f32x4 acc[4][4];
    const f32x4 zz = {0.f, 0.f, 0.f, 0.f};
#pragma unroll
    for (int mi = 0; mi < 4; ++mi)
#pragma unroll
        for (int ni = 0; ni < 4; ++ni) acc[mi][ni] = zz;

    for (int kc = 0; kc < K; kc += 128) {
        __syncthreads();
#pragma unroll
        for (int i = 0; i < CHUNKS / T; ++i) {
            const int c = i * T + t;
            const int row = c >> 4, cc = c & 15;
            const int gr = m0 + row;
            f16x8 v = (gr < M) ? *(const f16x8*)(A + (size_t)gr * K + kc + cc * 8)
                               : f16x8_zero();
            Atile[(row * 16 + cc) ^ (row & 7)] = v;
        }
        __syncthreads();
#pragma unroll
        for (int ks = 0; ks < 4; ++ks) {
            f16x8 af[4], bf[4];
#pragma unroll
            for (int mi = 0; mi < 4; ++mi) {
                const int row = wm * 64 + mi * 16 + l15;
                af[mi] = Atile[(row * 16 + ks * 4 + lg) ^ (row & 7)];
            }
#pragma unroll
            for (int ni = 0; ni < 4; ++ni) {
                const int col = n0 + wn * 64 + ni * 16 + l15;
                bf[ni] = *(const f16x8*)(Wt + (size_t)col * K + kc + ks * 32 + lg * 8);
            }
#pragma unroll
            for (int mi = 0; mi < 4; ++mi)
#pragma unroll
                for (int ni = 0; ni < 4; ++ni)
                    acc[mi][ni] = __builtin_amdgcn_mfma_f32_16x16x32_f16(
                        af[mi], bf[ni], acc[mi][ni], 0, 0, 0);
        }
    }
    const int head = (n0 + wn * 64) >> 6;
    float a4s[4], a4d[4];
#pragma unroll
    for (int ni = 0; ni < 4; ++ni) {
        a4s[ni] = a_s[head * 64 + ni * 16 + l15];
        a4d[ni] = a_d[head * 64 + ni * 16 + l15];
    }
#pragma unroll
    for (int mi = 0; mi < 4; ++mi)
#pragma unroll
        for (int j = 0; j < 4; ++j) {
            const int r = m0 + wm * 64 + mi * 16 + lg * 4 + j;
            if (r < M) {
                float s1 = 0.f, s2 = 0.f;
#pragma unroll
                for (int ni = 0; ni < 4; ++ni) {
                    const float v = acc[mi][ni][j];
                    s1 += v * a4s[ni];
                    s2 += v * a4d[ni];
                    hout[(size_t)r * Nn + n0 + wn * 64 + ni * 16 + l15] = (_Float16)v;
                }
#pragma unroll
                for (int o = 8; o; o >>= 1) {
                    s1 += __shfl_xor(s1, o);
                    s2 += __shfl_xor(s2, o);
                }
                if (l15 == 0) {
                    als[(size_t)r * H + head] = s1;
                    ald[(size_t)r * H + head] = s2;
                }
            }
        }
}

// ---------------- aggregation: per-wave LDS slices, chunk prefetch, ----------
// 4-way split accumulators (4 gathers in flight), 4 nodes / 256-thr block -----

// H=4 (F=256): one wave per node; lane t covers channels t*4..t*4+3, head=t>>4.
__global__ __launch_bounds__(256) void gat_agg_h4(
    const __half* __restrict__ hhf, const float4* __restrict__ als4,
    const float4* __restrict__ ald4, const int* __restrict__ csrsrc,
    const int* __restrict__ offv, const float* __restrict__ bias,
    __half* __restrict__ outh, int N) {
    __shared__ int sidAll[4][64];
    __shared__ float wAll[4][64 * 4];
    const int wv = threadIdx.x >> 6;
    const int t = threadIdx.x & 63;
    const int n = blockIdx.x * 4 + wv;
    if (n >= N) return;
    const int hh = t >> 4;
    int* sid = sidAll[wv];
    float* wsh = wAll[wv];
    const int start = offv[n];
    const int deg = offv[n + 1] - start;
    const float4 ad = ald4[n];
    const float4 asf = als4[n];
    float wself;
    {
        float4 w4;
        w4.x = __expf(LRELU(asf.x + ad.x));
        w4.y = __expf(LRELU(asf.y + ad.y));
        w4.z = __expf(LRELU(asf.z + ad.z));
        w4.w = __expf(LRELU(asf.w + ad.w));
        float r = w4.x;
        r = (hh == 1) ? w4.y : r;
        r = (hh == 2) ? w4.z : r;
        r = (hh == 3) ? w4.w : r;
        wself = r;
    }
    float ac0[4], ac1[4] = {}, ac2[4] = {}, ac3[4] = {};
    {
        float2 raw = *(const float2*)(hhf + (size_t)n * 256 + t * 4);
        __half2 h0 = *(__half2*)&raw.x;
        __half2 h1 = *(__half2*)&raw.y;
        float2 a0 = __half22float2(h0), a1 = __half22float2(h1);
        ac0[0] = a0.x * wself; ac0[1] = a0.y * wself;
        ac0[2] = a1.x * wself; ac0[3] = a1.y * wself;
    }
    float ds0 = wself, ds1 = 0.f, ds2 = 0.f, ds3 = 0.f;

    const int nchunks = (deg + 63) >> 6;
    int s_cur = 0;
    float4 av_cur = {0.f, 0.f, 0.f, 0.f};
    if (nchunks > 0 && t < deg) {
        s_cur = csrsrc[start + t];
        av_cur = als4[s_cur];
    }
    for (int c = 0; c < nchunks; ++c) {
        const int base = c * 64;
        const int nb = min(64, deg - base);
        float4 w4 = {0.f, 0.f, 0.f, 0.f};
        if (t < nb) {
            w4.x = __expf(LRELU(av_cur.x + ad.x));
            w4.y = __expf(LRELU(av_cur.y + ad.y));
            w4.z = __expf(LRELU(av_cur.z + ad.z));
            w4.w = __expf(LRELU(av_cur.w + ad.w));
        }
        sid[t] = s_cur;
        *(float4*)(wsh + t * 4) = w4;
        __threadfence_block();   // same-wave LDS write->read ordering
        // prefetch next chunk's csr + als gather (hidden under accumulate)
        int s_nxt = 0;
        float4 av_nxt = {0.f, 0.f, 0.f, 0.f};
        if (c + 1 < nchunks && t < deg - base - 64) {
            s_nxt = csrsrc[start + base + 64 + t];
            av_nxt = als4[s_nxt];
        }
        // accumulate: 4 gathers in flight
        int i = 0;
        for (; i + 3 < nb; i += 4) {
            const int s0 = sid[i + 0], s1 = sid[i + 1], s2 = sid[i + 2], s3 = sid[i + 3];
            const float w0 = wsh[(i + 0) * 4 + hh], w1 = wsh[(i + 1) * 4 + hh];
            const float w2 = wsh[(i + 2) * 4 + hh], w3 = wsh[(i + 3) * 4 + hh];
            float2 r0 = *(const float2*)(hhf + (size_t)s0 * 256 + t * 4);
            float2 r1 = *(const float2*)(hhf + (size_t)s1 * 256 + t * 4);
            float2 r2 = *(const float2*)(hhf + (size_t)s2 * 256 + t * 4);
            float2 r3 = *(const float2*)(hhf + (size_t)s3 * 256 + t * 4);
            float2 f00 = __half22float2(*(__half2*)&r0.x), f01 = __half22float2(*(__half2*)&r0.y);
            float2 f10 = __half22float2(*(__half2*)&r1.x), f11 = __half22float2(*(__half2*)&r1.y);
            float2 f20 = __half22float2(*(__half2*)&r2.x), f21 = __half22float2(*(__half2*)&r2.y);
            float2 f30 = __half22float2(*(__half2*)&r3.x), f31 = __half22float2(*(__half2*)&r3.y);
            ds0 += w0; ds1 += w1; ds2 += w2; ds3 += w3;
            ac0[0] += f00.x * w0; ac0[1] += f00.y * w0; ac0[2] += f01.x * w0; ac0[3] += f01.y * w0;
            ac1[0] += f10.x * w1; ac1[1] += f10.y * w1; ac1[2] += f11.x * w1; ac1[3] += f11.y * w1;
            ac2[0] += f20.x * w2; ac2[1] += f20.y * w2; ac2[2] += f21.x * w2; ac2[3] += f21.y * w2;
            ac3[0] += f30.x * w3; ac3[1] += f30.y * w3; ac3[2] += f31.x * w3; ac3[3] += f31.y * w3;
        }
        for (; i < nb; ++i) {
            const int s0 = sid[i];
            const float w0 = wsh[i * 4 + hh];
            float2 r0 = *(const float2*)(hhf + (size_t)s0 * 256 + t * 4);
            float2 f00 = __half22float2(*(__half2*)&r0.x), f01 = __half22float2(*(__half2*)&r0.y);
            ds0 += w0;
            ac0[0] += f00.x * w0; ac0[1] += f00.y * w0; ac0[2] += f01.x * w0; ac0[3] += f01.y * w0;
        }
        __threadfence_block();   // reads done before next chunk's writes
        s_cur = s_nxt;
        av_cur = av_nxt;
    }
    const float inv = 1.f / (ds0 + ds1 + ds2 + ds3 + 1e-16f);
    const float4 bv = *(const float4*)(bias + t * 4);
    float4 o4;
    o4.x = (ac0[0] + ac1[0] + ac2[0] + ac3[0]) * inv + bv.x;
    o4.y = (ac0[1] + ac1[1] + ac2[1] + ac3[1]) * inv + bv.y;
    o4.z = (ac0[2] + ac1[2] + ac2[2] + ac3[2]) * inv + bv.z;
    o4.w = (ac0[3] + ac1[3] + ac2[3] + ac3[3]) * inv + bv.w;
    // ELU
    o4.x = (o4.x > 0.f) ? o4.x : (__expf(o4.x) - 1.f);
    o4.y = (o4.y > 0.f) ? o4.y : (__expf(o4.y) - 1.f);
    o4.z = (o4.z > 0.f) ? o4.z : (__expf(o4.z) - 1.f);
    o4.w = (o4.w > 0.f) ? o4.w : (__expf(o4.w) - 1.f);
    __half2 p0 = __floats2half2_rn(o4.x, o4.y);
    __half2 p1 = __floats2half2_rn(o4.z, o4.w);
    float2 st;
    *(__half2*)&st.x = p0;
    *(__half2*)&st.y = p1;
    *(float2*)(outh + (size_t)n * 256 + t * 4) = st;
}

// H=1 (F=64) + ReLU + classifier + log_softmax; wave-parallel classifier.
__global__ __launch_bounds__(256) void gat_agg_h1_cls(
    const __half* __restrict__ hhf, const float* __restrict__ als,
    const float* __restrict__ ald, const int* __restrict__ csrsrc,
    const int* __restrict__ offv, const float* __restrict__ bias,
    const float* __restrict__ cW1, const float* __restrict__ cb1,
    const float* __restrict__ cW2, const float* __restrict__ cb2,
    float* __restrict__ outp, int N) {
    __shared__ float w1s[2048];   // cW1 [64][32]
    __shared__ float w2s[64];     // cW2 [32][2]
    __shared__ int sidAll[4][64];
    __shared__ float wAll[4][64];
    __shared__ float xsAll[4][64];
    for (int i = threadIdx.x; i < 2048; i += 256) w1s[i] = cW1[i];
    if (threadIdx.x < 64) w2s[threadIdx.x] = cW2[threadIdx.x];
    __syncthreads();   // uniform, once
    const int wv = threadIdx.x >> 6;
    const int t = threadIdx.x & 63;
    const int n = blockIdx.x * 4 + wv;
    if (n >= N) return;
    int* sid = sidAll[wv];
    float* wsh = wAll[wv];
    float* xs = xsAll[wv];
    const int start = offv[n];
    const int deg = offv[n + 1] - start;
    const float ad = ald[n];
    const float wself = __expf(LRELU(als[n] + ad));
    float a0 = __half2float(hhf[(size_t)n * 64 + t]) * wself;
    float a1 = 0.f, a2 = 0.f, a3 = 0.f;
    float d0 = wself, d1 = 0.f, d2 = 0.f, d3 = 0.f;

    const int nchunks = (deg + 63) >> 6;
    int s_cur = 0;
    float al_cur = 0.f;
    if (nchunks > 0 && t < deg) {
        s_cur = csrsrc[start + t];
        al_cur = als[s_cur];
    }
    for (int c = 0; c < nchunks; ++c) {
        const int base = c * 64;
        const int nb = min(64, deg - base);
        float w = 0.f;
        if (t < nb) w = __expf(LRELU(al_cur + ad));
        sid[t] = s_cur;
        wsh[t] = w;
        __threadfence_block();
        int s_nxt = 0;
        float al_nxt = 0.f;
        if (c + 1 < nchunks && t < deg - base - 64) {
            s_nxt = csrsrc[start + base + 64 + t];
            al_nxt = als[s_nxt];
        }
        int i = 0;
        for (; i + 3 < nb; i += 4) {
            const int s0 = sid[i + 0], s1 = sid[i + 1], s2 = sid[i + 2], s3 = sid[i + 3];
            const float w0 = wsh[i + 0], w1 = wsh[i + 1], w2 = wsh[i + 2], w3 = wsh[i + 3];
            const float h0 = __half2float(hhf[(size_t)s0 * 64 + t]);
            const float h1 = __half2float(hhf[(size_t)s1 * 64 + t]);
            const float h2 = __half2float(hhf[(size_t)s2 * 64 + t]);
            const float h3 = __half2float(hhf[(size_t)s3 * 64 + t]);
            d0 += w0; d1 += w1; d2 += w2; d3 += w3;
            a0 += h0 * w0; a1 += h1 * w1; a2 += h2 * w2; a3 += h3 * w3;
        }
        for (; i < nb; ++i) {
            const int s0 = sid[i];
            const float w0 = wsh[i];
            d0 += w0;
            a0 += __half2float(hhf[(size_t)s0 * 64 + t]) * w0;
        }
        __threadfence_block();
        s_cur = s_nxt;
        al_cur = al_nxt;
    }
    const float val = fmaxf((a0 + a1 + a2 + a3) / (d0 + d1 + d2 + d3 + 1e-16f)
                            + bias[t], 0.f);
    // ---- classifier, wave-parallel ----
    xs[t] = val;
    __threadfence_block();
    const int j = t & 31;
    const int half = t >> 5;
    float s1 = 0.f;
#pragma unroll
    for (int cc = 0; cc < 32; ++cc) {
        const int c = half * 32 + cc;
        s1 += xs[c] * w1s[c * 32 + j];
    }
    s1 += __shfl_xor(s1, 32);
    const float hid = fmaxf(s1 + cb1[j], 0.f);
    const int k = t & 1, jj = t >> 1;
    const float hjj = __shfl(hid, jj);
    float s2 = hjj * w2s[jj * 2 + k];
#pragma unroll
    for (int o = 2; o < 64; o <<= 1) s2 += __shfl_xor(s2, o);
    s2 += cb2[k];
    const float a = __shfl(s2, 0);
    const float b = __shfl(s2, 1);
    const float mm = fmaxf(a, b);
    const float lse = mm + logf(__expf(a - mm) + __expf(b - mm));
    if (t < 2) outp[(size_t)n * 2 + t] = s2 - lse;
}

extern "C" void kernel_launch(void* const* d_in, const int* in_sizes, int n_in,
                              void* d_out, int out_size, void* d_ws, size_t ws_size,
                              hipStream_t stream) {
    const float* x   = (const float*)d_in[0];
    const int*   ei  = (const int*)d_in[1];
    const float* W1  = (const float*)d_in[2];
    const float* a1s = (const float*)d_in[3];
    const float* a1d = (const float*)d_in[4];
    const float* b1  = (const float*)d_in[5];
    const float* W2  = (const float*)d_in[6];
    const float* a2s = (const float*)d_in[7];
    const float* a2d = (const float*)d_in[8];
    const float* b2  = (const float*)d_in[9];
    const float* W3  = (const float*)d_in[10];
    const float* a3s = (const float*)d_in[11];
    const float* a3d = (const float*)d_in[12];
    const float* b3  = (const float*)d_in[13];
    const float* cW1 = (const float*)d_in[14];
    const float* cb1 = (const float*)d_in[15];
    const float* cW2 = (const float*)d_in[16];
    const float* cb2 = (const float*)d_in[17];

    const int N = in_sizes[0] / 128;   // 50000
    const int E = in_sizes[1] / 2;     // 500000
    const int* srcv = ei;
    const int* dstv = ei + E;

    // workspace layout, all segments 16B-aligned
    char* p = (char*)d_ws;
    _Float16* slotA = (_Float16*)p; p += (size_t)N * 256 * 2;   // h1h / h2h / h3h
    _Float16* slotB = (_Float16*)p; p += (size_t)N * 256 * 2;   // a1h / a2h
    _Float16* slotC = (_Float16*)p; p += (size_t)N * 128 * 2;   // xh
    float* als = (float*)p; p += (size_t)N * 4 * 4;
    float* ald = (float*)p; p += (size_t)N * 4 * 4;
    int* cnt = (int*)p; p += (size_t)N * 4;
    int* offv = (int*)p; p += (size_t)(N + 4) * 4;
    int* csr = (int*)p; p += (size_t)E * 4;
    _Float16* Wt1 = (_Float16*)p; p += (size_t)128 * 256 * 2;
    _Float16* Wt2 = (_Float16*)p; p += (size_t)256 * 256 * 2;
    _Float16* Wt3 = (_Float16*)p; p += (size_t)256 * 64 * 2;
    int* bsum = (int*)p;

    // weight/input conversions (independent of CSR)
    prep_w16<<<(128 * 256 + 255) / 256, 256, 0, stream>>>(W1, Wt1, 128, 256);
    prep_w16<<<(256 * 256 + 255) / 256, 256, 0, stream>>>(W2, Wt2, 256, 256);
    prep_w16<<<(256 * 64 + 255) / 256, 256, 0, stream>>>(W3, Wt3, 256, 64);
    cvt_f16<<<(N * 128 / 4 + 255) / 256, 256, 0, stream>>>(x, slotC, N * 128 / 4);

    // CSR by destination
    const int NB = (N + 1023) / 1024;   // 49
    hipMemsetAsync(cnt, 0, (size_t)N * sizeof(int), stream);
    hist_kernel<<<(E + 255) / 256, 256, 0, stream>>>(dstv, cnt, E);
    scan_blk<<<NB, 256, 0, stream>>>(cnt, offv, bsum, N);
    scan_top<<<1, 64, 0, stream>>>(bsum, offv, NB, N);
    scan_add<<<NB, 256, 0, stream>>>(offv, bsum, N);
    hipMemsetAsync(cnt, 0, (size_t)N * sizeof(int), stream);
    fill_kernel<<<(E + 255) / 256, 256, 0, stream>>>(dstv, srcv, offv, cnt, csr, E);

    const int MB128 = (N + 127) / 128;   // 391
    const int MB256 = (N + 255) / 256;   // 196
    const int AGG = (N + 3) / 4;         // 12500

    // ---- layer 1 (128 -> 256, H=4, ELU) ----
    gemm_f16_fused<2, 4, 128, 4><<<dim3(MB128, 1), 512, 0, stream>>>(
        slotC, Wt1, a1s, a1d, slotA, als, ald, N, 256);
    gat_agg_h4<<<AGG, 256, 0, stream>>>((const __half*)slotA, (const float4*)als,
                                        (const float4*)ald, csr, offv, b1,
                                        (__half*)slotB, N);

    // ---- layer 2 (256 -> 256, H=4, ELU) ----
    gemm_f16_fused<2, 4, 256, 4><<<dim3(MB128, 1), 512, 0, stream>>>(
        slotB, Wt2, a2s, a2d, slotA, als, ald, N, 256);
    gat_agg_h4<<<AGG, 256, 0, stream>>>((const __half*)slotA, (const float4*)als,
                                        (const float4*)ald, csr, offv, b2,
                                        (__half*)slotB, N);

    // ---- layer 3 (256 -> 64, H=1) + agg + classifier + log_softmax ----
    gemm_f16_fused<4, 1, 256, 1><<<dim3(MB256, 1), 256, 0, stream>>>(
        slotB, Wt3, a3s, a3d, slotA, als, ald, N, 64);
    gat_agg_h1_cls<<<AGG, 256, 0, stream>>>((const __half*)slotA, als, ald, csr,
                                            offv, b3, cW1, cb1, cW2, cb2,
                                            (float*)d_out, N);
}

// Round 10
// 275.006 us; speedup vs baseline: 1.0508x; 1.0508x over previous
//
#include <hip/hip_runtime.h>
#include <hip/hip_fp16.h>

#define LRELU(v) ((v) > 0.f ? (v) : 0.2f * (v))
#define LOG2E 1.44269504088896340736f

typedef _Float16 f16x8 __attribute__((ext_vector_type(8)));
typedef _Float16 f16x4 __attribute__((ext_vector_type(4)));
typedef float f32x4 __attribute__((ext_vector_type(4)));

__device__ __forceinline__ float fexp2(float x) {
    return __builtin_amdgcn_exp2f(x);   // v_exp_f32
}

__device__ __forceinline__ f16x8 f16x8_zero() {
    f16x8 v;
#pragma unroll
    for (int j = 0; j < 8; ++j) v[j] = (_Float16)0.f;
    return v;
}

// ---------------- CSR construction ----------------
__global__ __launch_bounds__(256) void hist_kernel(const int* __restrict__ dst,
                                                   int* __restrict__ cnt, int E) {
    int e = blockIdx.x * 256 + threadIdx.x;
    if (e < E) atomicAdd(&cnt[dst[e]], 1);
}

__global__ __launch_bounds__(256) void scan_blk(const int* __restrict__ cnt,
                                                int* __restrict__ offv,
                                                int* __restrict__ bsum, int N) {
    __shared__ int sh[256];
    const int t = threadIdx.x;
    const int base = blockIdx.x * 1024 + t * 4;
    int v0 = (base + 0 < N) ? cnt[base + 0] : 0;
    int v1 = (base + 1 < N) ? cnt[base + 1] : 0;
    int v2 = (base + 2 < N) ? cnt[base + 2] : 0;
    int v3 = (base + 3 < N) ? cnt[base + 3] : 0;
    const int T = v0 + v1 + v2 + v3;
    sh[t] = T;
    __syncthreads();
    for (int o = 1; o < 256; o <<= 1) {
        int x = (t >= o) ? sh[t - o] : 0;
        __syncthreads();
        sh[t] += x;
        __syncthreads();
    }
    const int excl = sh[t] - T;
    if (t == 255) bsum[blockIdx.x] = sh[255];
    if (base + 0 < N) offv[base + 0] = excl;
    if (base + 1 < N) offv[base + 1] = excl + v0;
    if (base + 2 < N) offv[base + 2] = excl + v0 + v1;
    if (base + 3 < N) offv[base + 3] = excl + v0 + v1 + v2;
}

__global__ __launch_bounds__(64) void scan_top(int* __restrict__ bsum,
                                               int* __restrict__ offv,
                                               int NB, int N) {
    const int t = threadIdx.x;
    const int v = (t < NB) ? bsum[t] : 0;
    int incl = v;
#pragma unroll
    for (int o = 1; o < 64; o <<= 1) {
        int x = __shfl_up(incl, o);
        if (t >= o) incl += x;
    }
    if (t < NB) bsum[t] = incl - v;
    if (t == NB - 1) offv[N] = incl;
}

__global__ __launch_bounds__(256) void scan_add(int* __restrict__ offv,
                                                const int* __restrict__ bsum, int N) {
    const int base = blockIdx.x * 1024 + threadIdx.x * 4;
    const int add = bsum[blockIdx.x];
#pragma unroll
    for (int i = 0; i < 4; ++i)
        if (base + i < N) offv[base + i] += add;
}

__global__ __launch_bounds__(256) void fill_kernel(const int* __restrict__ dst,
                                                   const int* __restrict__ srcv,
                                                   const int* __restrict__ offv,
                                                   int* __restrict__ cur,
                                                   int* __restrict__ csrsrc, int E) {
    int e = blockIdx.x * 256 + threadIdx.x;
    if (e < E) {
        int d = dst[e];
        int p = atomicAdd(&cur[d], 1);
        csrsrc[offv[d] + p] = srcv[e];
    }
}

// ---------------- weight prep: all three transposes in one dispatch ----------
__global__ __launch_bounds__(256) void prep_w_all(
    const float* __restrict__ W1, const float* __restrict__ W2,
    const float* __restrict__ W3, _Float16* __restrict__ Wt1,
    _Float16* __restrict__ Wt2, _Float16* __restrict__ Wt3) {
    const int S1 = 128 * 256, S2 = 256 * 256, S3 = 256 * 64;
    int idx = blockIdx.x * 256 + threadIdx.x;
    if (idx < S1) {
        int k = idx >> 8, nn = idx & 255;
        Wt1[nn * 128 + k] = (_Float16)W1[idx];
    } else if (idx < S1 + S2) {
        int i = idx - S1;
        int k = i >> 8, nn = i & 255;
        Wt2[nn * 256 + k] = (_Float16)W2[idx - S1];
    } else if (idx < S1 + S2 + S3) {
        int i = idx - S1 - S2;
        int k = i >> 6, nn = i & 63;
        Wt3[nn * 256 + k] = (_Float16)W3[i];
    }
}

// ---------------- f16 MFMA GEMM, LDS-staged A, fused alpha (log2-domain) -----
// AF32: A is fp32 (layer 1's x), converted during staging.
template <int WM, int WN, int K, int H, bool AF32>
__global__ __launch_bounds__(WM * WN * 64) void gemm_f16_fused(
    const void* __restrict__ Av, const _Float16* __restrict__ Wt,
    const float* __restrict__ a_s, const float* __restrict__ a_d,
    _Float16* __restrict__ hout, float* __restrict__ als,
    float* __restrict__ ald, int M, int Nn) {
    constexpr int BM = WM * 64;
    constexpr int T = WM * WN * 64;
    constexpr int CHUNKS = BM * 16;
    __shared__ f16x8 Atile[BM * 16];
    const _Float16* A16 = (const _Float16*)Av;
    const float* A32 = (const float*)Av;
    const int t = threadIdx.x;
    const int lane = t & 63;
    const int wv = t >> 6;
    const int wm = wv / WN, wn = wv % WN;
    const int m0 = blockIdx.x * BM;
    const int n0 = blockIdx.y * (WN * 64);
    const int l15 = lane & 15, lg = lane >> 4;

    f32x4 acc[4][4];
    const f32x4 zz = {0.f, 0.f, 0.f, 0.f};
#pragma unroll
    for (int mi = 0; mi < 4; ++mi)
#pragma unroll
        for (int ni = 0; ni < 4; ++ni) acc[mi][ni] = zz;

    for (int kc = 0; kc < K; kc += 128) {
        __syncthreads();
#pragma unroll
        for (int i = 0; i < CHUNKS / T; ++i) {
            const int c = i * T + t;
            const int row = c >> 4, cc = c & 15;
            const int gr = m0 + row;
            f16x8 v;
            if (gr < M) {
                if constexpr (AF32) {
                    float4 p = *(const float4*)(A32 + (size_t)gr * K + kc + cc * 8);
                    float4 q = *(const float4*)(A32 + (size_t)gr * K + kc + cc * 8 + 4);
                    v[0] = (_Float16)p.x; v[1] = (_Float16)p.y;
                    v[2] = (_Float16)p.z; v[3] = (_Float16)p.w;
                    v[4] = (_Float16)q.x; v[5] = (_Float16)q.y;
                    v[6] = (_Float16)q.z; v[7] = (_Float16)q.w;
                } else {
                    v = *(const f16x8*)(A16 + (size_t)gr * K + kc + cc * 8);
                }
            } else {
                v = f16x8_zero();
            }
            Atile[(row * 16 + cc) ^ (row & 7)] = v;
        }
        __syncthreads();
#pragma unroll
        for (int ks = 0; ks < 4; ++ks) {
            f16x8 af[4], bf[4];
#pragma unroll
            for (int mi = 0; mi < 4; ++mi) {
                const int row = wm * 64 + mi * 16 + l15;
                af[mi] = Atile[(row * 16 + ks * 4 + lg) ^ (row & 7)];
            }
#pragma unroll
            for (int ni = 0; ni < 4; ++ni) {
                const int col = n0 + wn * 64 + ni * 16 + l15;
                bf[ni] = *(const f16x8*)(Wt + (size_t)col * K + kc + ks * 32 + lg * 8);
            }
#pragma unroll
            for (int mi = 0; mi < 4; ++mi)
#pragma unroll
                for (int ni = 0; ni < 4; ++ni)
                    acc[mi][ni] = __builtin_amdgcn_mfma_f32_16x16x32_f16(
                        af[mi], bf[ni], acc[mi][ni], 0, 0, 0);
        }
    }
    // epilogue: fused alpha dots, pre-scaled by log2(e) so agg uses exp2
    const int head = (n0 + wn * 64) >> 6;
    float a4s[4], a4d[4];
#pragma unroll
    for (int ni = 0; ni < 4; ++ni) {
        a4s[ni] = a_s[head * 64 + ni * 16 + l15] * LOG2E;
        a4d[ni] = a_d[head * 64 + ni * 16 + l15] * LOG2E;
    }
#pragma unroll
    for (int mi = 0; mi < 4; ++mi)
#pragma unroll
        for (int j = 0; j < 4; ++j) {
            const int r = m0 + wm * 64 + mi * 16 + lg * 4 + j;
            if (r < M) {
                float s1 = 0.f, s2 = 0.f;
#pragma unroll
                for (int ni = 0; ni < 4; ++ni) {
                    const float v = acc[mi][ni][j];
                    s1 += v * a4s[ni];
                    s2 += v * a4d[ni];
                    hout[(size_t)r * Nn + n0 + wn * 64 + ni * 16 + l15] = (_Float16)v;
                }
#pragma unroll
                for (int o = 8; o; o >>= 1) {
                    s1 += __shfl_xor(s1, o);
                    s2 += __shfl_xor(s2, o);
                }
                if (l15 == 0) {
                    als[(size_t)r * H + head] = s1;
                    ald[(size_t)r * H + head] = s2;
                }
            }
        }
}

// ---------------- aggregation: lean inner loop ----------
// exp2-domain weights, deferred dsum (lane-partial + end butterfly),
// fma_mix accumulate, b128-batched LDS reads, per-wave LDS slices.

__device__ __forceinline__ float sel4(float4 v, int h) {
    float r = v.x;
    r = (h == 1) ? v.y : r;
    r = (h == 2) ? v.z : r;
    r = (h == 3) ? v.w : r;
    return r;
}

// H=4 (F=256): one wave per node; lane t covers channels t*4..t*4+3, head=t>>4.
__global__ __launch_bounds__(256) void gat_agg_h4(
    const _Float16* __restrict__ hhf, const float4* __restrict__ als4,
    const float4* __restrict__ ald4, const int* __restrict__ csrsrc,
    const int* __restrict__ offv, const float* __restrict__ bias,
    _Float16* __restrict__ outh, int N) {
    __shared__ int sidAll[4][64];
    __shared__ float wTAll[4][4][64];   // [wave][head][edge]
    const int wv = threadIdx.x >> 6;
    const int t = threadIdx.x & 63;
    const int n = blockIdx.x * 4 + wv;
    if (n >= N) return;
    const int hh = t >> 4;
    int* sid = sidAll[wv];
    float (*wT)[64] = wTAll[wv];
    const int start = offv[n];
    const int deg = offv[n + 1] - start;
    const float4 ad = ald4[n];
    const float4 asf = als4[n];
    float4 ws4;
    ws4.x = fexp2(LRELU(asf.x + ad.x));
    ws4.y = fexp2(LRELU(asf.y + ad.y));
    ws4.z = fexp2(LRELU(asf.z + ad.z));
    ws4.w = fexp2(LRELU(asf.w + ad.w));
    const float wself = sel4(ws4, hh);
    float accA[4], accB[4] = {};
    {
        const f16x4 hv = *(const f16x4*)(hhf + (size_t)n * 256 + t * 4);
#pragma unroll
        for (int c = 0; c < 4; ++c) accA[c] = (float)hv[c] * wself;
    }
    float4 wacc = {0.f, 0.f, 0.f, 0.f};   // per-lane partial denominators
    if (t == 0) wacc = ws4;               // self term counted once

    for (int base = 0; base < deg; base += 64) {
        const int nb = min(64, deg - base);
        int s = 0;
        float4 w4 = {0.f, 0.f, 0.f, 0.f};
        if (t < nb) {
            s = csrsrc[start + base + t];
            const float4 av = als4[s];
            w4.x = fexp2(LRELU(av.x + ad.x));
            w4.y = fexp2(LRELU(av.y + ad.y));
            w4.z = fexp2(LRELU(av.z + ad.z));
            w4.w = fexp2(LRELU(av.w + ad.w));
            wacc.x += w4.x; wacc.y += w4.y;
            wacc.z += w4.z; wacc.w += w4.w;
        }
        sid[t] = s;
        wT[0][t] = w4.x;
        wT[1][t] = w4.y;
        wT[2][t] = w4.z;
        wT[3][t] = w4.w;
        __threadfence_block();   // same-wave LDS write->read ordering
        int i = 0;
        for (; i + 3 < nb; i += 4) {
            const int4 ss = *(const int4*)&sid[i];          // uniform b128
            const float4 ww = *(const float4*)&wT[hh][i];   // b128, head slice
            const f16x4 h0 = *(const f16x4*)(hhf + (size_t)ss.x * 256 + t * 4);
            const f16x4 h1 = *(const f16x4*)(hhf + (size_t)ss.y * 256 + t * 4);
            const f16x4 h2 = *(const f16x4*)(hhf + (size_t)ss.z * 256 + t * 4);
            const f16x4 h3 = *(const f16x4*)(hhf + (size_t)ss.w * 256 + t * 4);
#pragma unroll
            for (int c = 0; c < 4; ++c) {
                accA[c] += (float)h0[c] * ww.x;
                accB[c] += (float)h1[c] * ww.y;
                accA[c] += (float)h2[c] * ww.z;
                accB[c] += (float)h3[c] * ww.w;
            }
        }
        for (; i < nb; ++i) {
            const int s0 = sid[i];
            const float w0 = wT[hh][i];
            const f16x4 h0 = *(const f16x4*)(hhf + (size_t)s0 * 256 + t * 4);
#pragma unroll
            for (int c = 0; c < 4; ++c) accA[c] += (float)h0[c] * w0;
        }
        __threadfence_block();   // reads done before next chunk's writes
    }
    // denominator: butterfly-sum the per-lane partials
#pragma unroll
    for (int o = 32; o; o >>= 1) {
        wacc.x += __shfl_xor(wacc.x, o);
        wacc.y += __shfl_xor(wacc.y, o);
        wacc.z += __shfl_xor(wacc.z, o);
        wacc.w += __shfl_xor(wacc.w, o);
    }
    const float inv = 1.f / (sel4(wacc, hh) + 1e-16f);
    const float4 bv = *(const float4*)(bias + t * 4);
    float o4[4];
#pragma unroll
    for (int c = 0; c < 4; ++c) o4[c] = (accA[c] + accB[c]) * inv;
    o4[0] += bv.x; o4[1] += bv.y; o4[2] += bv.z; o4[3] += bv.w;
    // ELU
#pragma unroll
    for (int c = 0; c < 4; ++c)
        o4[c] = (o4[c] > 0.f) ? o4[c] : (__expf(o4[c]) - 1.f);
    f16x4 st;
#pragma unroll
    for (int c = 0; c < 4; ++c) st[c] = (_Float16)o4[c];
    *(f16x4*)(outh + (size_t)n * 256 + t * 4) = st;
}

// H=1 (F=64) + ReLU + classifier + log_softmax; wave-parallel classifier.
__global__ __launch_bounds__(256) void gat_agg_h1_cls(
    const _Float16* __restrict__ hhf, const float* __restrict__ als,
    const float* __restrict__ ald, const int* __restrict__ csrsrc,
    const int* __restrict__ offv, const float* __restrict__ bias,
    const float* __restrict__ cW1, const float* __restrict__ cb1,
    const float* __restrict__ cW2, const float* __restrict__ cb2,
    float* __restrict__ outp, int N) {
    __shared__ float w1s[2048];   // cW1 [64][32]
    __shared__ float w2s[64];     // cW2 [32][2]
    __shared__ int sidAll[4][64];
    __shared__ float wAll[4][64];
    __shared__ float xsAll[4][64];
    for (int i = threadIdx.x; i < 2048; i += 256) w1s[i] = cW1[i];
    if (threadIdx.x < 64) w2s[threadIdx.x] = cW2[threadIdx.x];
    __syncthreads();   // uniform, once
    const int wv = threadIdx.x >> 6;
    const int t = threadIdx.x & 63;
    const int n = blockIdx.x * 4 + wv;
    if (n >= N) return;
    int* sid = sidAll[wv];
    float* wsh = wAll[wv];
    float* xs = xsAll[wv];
    const int start = offv[n];
    const int deg = offv[n + 1] - start;
    const float ad = ald[n];
    const float wself = fexp2(LRELU(als[n] + ad));
    float a0 = (float)hhf[(size_t)n * 64 + t] * wself;
    float a1 = 0.f, a2 = 0.f, a3 = 0.f;
    float wacc = (t == 0) ? wself : 0.f;

    for (int base = 0; base < deg; base += 64) {
        const int nb = min(64, deg - base);
        int s = 0;
        float w = 0.f;
        if (t < nb) {
            s = csrsrc[start + base + t];
            w = fexp2(LRELU(als[s] + ad));
            wacc += w;
        }
        sid[t] = s;
        wsh[t] = w;
        __threadfence_block();
        int i = 0;
        for (; i + 3 < nb; i += 4) {
            const int4 ss = *(const int4*)&sid[i];
            const float4 ww = *(const float4*)&wsh[i];
            a0 += (float)hhf[(size_t)ss.x * 64 + t] * ww.x;
            a1 += (float)hhf[(size_t)ss.y * 64 + t] * ww.y;
            a2 += (float)hhf[(size_t)ss.z * 64 + t] * ww.z;
            a3 += (float)hhf[(size_t)ss.w * 64 + t] * ww.w;
        }
        for (; i < nb; ++i) {
            a0 += (float)hhf[(size_t)sid[i] * 64 + t] * wsh[i];
        }
        __threadfence_block();
    }
#pragma unroll
    for (int o = 32; o; o >>= 1) wacc += __shfl_xor(wacc, o);
    const float val = fmaxf((a0 + a1 + a2 + a3) / (wacc + 1e-16f) + bias[t], 0.f);
    // ---- classifier, wave-parallel ----
    xs[t] = val;
    __threadfence_block();
    const int j = t & 31;
    const int half = t >> 5;
    float s1 = 0.f;
#pragma unroll
    for (int cc = 0; cc < 32; ++cc) {
        const int c = half * 32 + cc;
        s1 += xs[c] * w1s[c * 32 + j];
    }
    s1 += __shfl_xor(s1, 32);
    const float hid = fmaxf(s1 + cb1[j], 0.f);
    const int k = t & 1, jj = t >> 1;
    const float hjj = __shfl(hid, jj);
    float s2 = hjj * w2s[jj * 2 + k];
#pragma unroll
    for (int o = 2; o < 64; o <<= 1) s2 += __shfl_xor(s2, o);
    s2 += cb2[k];
    const float a = __shfl(s2, 0);
    const float b = __shfl(s2, 1);
    const float mm = fmaxf(a, b);
    const float lse = mm + logf(__expf(a - mm) + __expf(b - mm));
    if (t < 2) outp[(size_t)n * 2 + t] = s2 - lse;
}

extern "C" void kernel_launch(void* const* d_in, const int* in_sizes, int n_in,
                              void* d_out, int out_size, void* d_ws, size_t ws_size,
                              hipStream_t stream) {
    const float* x   = (const float*)d_in[0];
    const int*   ei  = (const int*)d_in[1];
    const float* W1  = (const float*)d_in[2];
    const float* a1s = (const float*)d_in[3];
    const float* a1d = (const float*)d_in[4];
    const float* b1  = (const float*)d_in[5];
    const float* W2  = (const float*)d_in[6];
    const float* a2s = (const float*)d_in[7];
    const float* a2d = (const float*)d_in[8];
    const float* b2  = (const float*)d_in[9];
    const float* W3  = (const float*)d_in[10];
    const float* a3s = (const float*)d_in[11];
    const float* a3d = (const float*)d_in[12];
    const float* b3  = (const float*)d_in[13];
    const float* cW1 = (const float*)d_in[14];
    const float* cb1 = (const float*)d_in[15];
    const float* cW2 = (const float*)d_in[16];
    const float* cb2 = (const float*)d_in[17];

    const int N = in_sizes[0] / 128;   // 50000
    const int E = in_sizes[1] / 2;     // 500000
    const int* srcv = ei;
    const int* dstv = ei + E;

    // workspace layout, all segments 16B-aligned
    char* p = (char*)d_ws;
    _Float16* slotA = (_Float16*)p; p += (size_t)N * 256 * 2;   // h1h / h2h / h3h
    _Float16* slotB = (_Float16*)p; p += (size_t)N * 256 * 2;   // a1h / a2h
    float* als = (float*)p; p += (size_t)N * 4 * 4;
    float* ald = (float*)p; p += (size_t)N * 4 * 4;
    int* cnt = (int*)p; p += (size_t)N * 4;
    int* offv = (int*)p; p += (size_t)(N + 4) * 4;
    int* csr = (int*)p; p += (size_t)E * 4;
    _Float16* Wt1 = (_Float16*)p; p += (size_t)128 * 256 * 2;
    _Float16* Wt2 = (_Float16*)p; p += (size_t)256 * 256 * 2;
    _Float16* Wt3 = (_Float16*)p; p += (size_t)256 * 64 * 2;
    int* bsum = (int*)p;

    // weight transposes (one dispatch)
    prep_w_all<<<(128 * 256 + 256 * 256 + 256 * 64 + 255) / 256, 256, 0, stream>>>(
        W1, W2, W3, Wt1, Wt2, Wt3);

    // CSR by destination
    const int NB = (N + 1023) / 1024;   // 49
    hipMemsetAsync(cnt, 0, (size_t)N * sizeof(int), stream);
    hist_kernel<<<(E + 255) / 256, 256, 0, stream>>>(dstv, cnt, E);
    scan_blk<<<NB, 256, 0, stream>>>(cnt, offv, bsum, N);
    scan_top<<<1, 64, 0, stream>>>(bsum, offv, NB, N);
    scan_add<<<NB, 256, 0, stream>>>(offv, bsum, N);
    hipMemsetAsync(cnt, 0, (size_t)N * sizeof(int), stream);
    fill_kernel<<<(E + 255) / 256, 256, 0, stream>>>(dstv, srcv, offv, cnt, csr, E);

    const int MB128 = (N + 127) / 128;   // 391
    const int MB256 = (N + 255) / 256;   // 196
    const int AGG = (N + 3) / 4;         // 12500

    // ---- layer 1 (128 -> 256, H=4, ELU); A = x fp32, converted in staging ----
    gemm_f16_fused<2, 4, 128, 4, true><<<dim3(MB128, 1), 512, 0, stream>>>(
        x, Wt1, a1s, a1d, slotA, als, ald, N, 256);
    gat_agg_h4<<<AGG, 256, 0, stream>>>(slotA, (const float4*)als,
                                        (const float4*)ald, csr, offv, b1,
                                        slotB, N);

    // ---- layer 2 (256 -> 256, H=4, ELU) ----
    gemm_f16_fused<2, 4, 256, 4, false><<<dim3(MB128, 1), 512, 0, stream>>>(
        slotB, Wt2, a2s, a2d, slotA, als, ald, N, 256);
    gat_agg_h4<<<AGG, 256, 0, stream>>>(slotA, (const float4*)als,
                                        (const float4*)ald, csr, offv, b2,
                                        slotB, N);

    // ---- layer 3 (256 -> 64, H=1) + agg + classifier + log_softmax ----
    gemm_f16_fused<4, 1, 256, 1, false><<<dim3(MB256, 1), 256, 0, stream>>>(
        slotB, Wt3, a3s, a3d, slotA, als, ald, N, 64);
    gat_agg_h1_cls<<<AGG, 256, 0, stream>>>(slotA, als, ald, csr,
                                            offv, b3, cW1, cb1, cW2, cb2,
                                            (float*)d_out, N);
}

// Round 11
// 272.392 us; speedup vs baseline: 1.0608x; 1.0096x over previous
//
#include <hip/hip_runtime.h>
#include <hip/hip_fp16.h>

#define LRELU(v) ((v) > 0.f ? (v) : 0.2f * (v))
#define LOG2E 1.44269504088896340736f

typedef _Float16 f16x8 __attribute__((ext_vector_type(8)));
typedef _Float16 f16x4 __attribute__((ext_vector_type(4)));
typedef float f32x4 __attribute__((ext_vector_type(4)));

__device__ __forceinline__ float fexp2(float x) {
    return __builtin_amdgcn_exp2f(x);   // v_exp_f32
}

__device__ __forceinline__ f16x8 f16x8_zero() {
    f16x8 v;
#pragma unroll
    for (int j = 0; j < 8; ++j) v[j] = (_Float16)0.f;
    return v;
}

// ---------------- CSR construction ----------------
__global__ __launch_bounds__(256) void hist_kernel(const int* __restrict__ dst,
                                                   int* __restrict__ cnt, int E) {
    int e = blockIdx.x * 256 + threadIdx.x;
    if (e < E) atomicAdd(&cnt[dst[e]], 1);
}

__global__ __launch_bounds__(256) void scan_blk(const int* __restrict__ cnt,
                                                int* __restrict__ offv,
                                                int* __restrict__ bsum, int N) {
    __shared__ int sh[256];
    const int t = threadIdx.x;
    const int base = blockIdx.x * 1024 + t * 4;
    int v0 = (base + 0 < N) ? cnt[base + 0] : 0;
    int v1 = (base + 1 < N) ? cnt[base + 1] : 0;
    int v2 = (base + 2 < N) ? cnt[base + 2] : 0;
    int v3 = (base + 3 < N) ? cnt[base + 3] : 0;
    const int T = v0 + v1 + v2 + v3;
    sh[t] = T;
    __syncthreads();
    for (int o = 1; o < 256; o <<= 1) {
        int x = (t >= o) ? sh[t - o] : 0;
        __syncthreads();
        sh[t] += x;
        __syncthreads();
    }
    const int excl = sh[t] - T;
    if (t == 255) bsum[blockIdx.x] = sh[255];
    if (base + 0 < N) offv[base + 0] = excl;
    if (base + 1 < N) offv[base + 1] = excl + v0;
    if (base + 2 < N) offv[base + 2] = excl + v0 + v1;
    if (base + 3 < N) offv[base + 3] = excl + v0 + v1 + v2;
}

__global__ __launch_bounds__(64) void scan_top(int* __restrict__ bsum,
                                               int* __restrict__ offv,
                                               int NB, int N) {
    const int t = threadIdx.x;
    const int v = (t < NB) ? bsum[t] : 0;
    int incl = v;
#pragma unroll
    for (int o = 1; o < 64; o <<= 1) {
        int x = __shfl_up(incl, o);
        if (t >= o) incl += x;
    }
    if (t < NB) bsum[t] = incl - v;
    if (t == NB - 1) offv[N] = incl;
}

__global__ __launch_bounds__(256) void scan_add(int* __restrict__ offv,
                                                const int* __restrict__ bsum, int N) {
    const int base = blockIdx.x * 1024 + threadIdx.x * 4;
    const int add = bsum[blockIdx.x];
#pragma unroll
    for (int i = 0; i < 4; ++i)
        if (base + i < N) offv[base + i] += add;
}

__global__ __launch_bounds__(256) void fill_kernel(const int* __restrict__ dst,
                                                   const int* __restrict__ srcv,
                                                   const int* __restrict__ offv,
                                                   int* __restrict__ cur,
                                                   int* __restrict__ csrsrc, int E) {
    int e = blockIdx.x * 256 + threadIdx.x;
    if (e < E) {
        int d = dst[e];
        int p = atomicAdd(&cur[d], 1);
        csrsrc[offv[d] + p] = srcv[e];
    }
}

// ---------------- weight prep: all three transposes in one dispatch ----------
__global__ __launch_bounds__(256) void prep_w_all(
    const float* __restrict__ W1, const float* __restrict__ W2,
    const float* __restrict__ W3, _Float16* __restrict__ Wt1,
    _Float16* __restrict__ Wt2, _Float16* __restrict__ Wt3) {
    const int S1 = 128 * 256, S2 = 256 * 256, S3 = 256 * 64;
    int idx = blockIdx.x * 256 + threadIdx.x;
    if (idx < S1) {
        int k = idx >> 8, nn = idx & 255;
        Wt1[nn * 128 + k] = (_Float16)W1[idx];
    } else if (idx < S1 + S2) {
        int i = idx - S1;
        int k = i >> 8, nn = i & 255;
        Wt2[nn * 256 + k] = (_Float16)W2[idx - S1];
    } else if (idx < S1 + S2 + S3) {
        int i = idx - S1 - S2;
        int k = i >> 6, nn = i & 63;
        Wt3[nn * 256 + k] = (_Float16)W3[i];
    }
}

// ---------------- f16 MFMA GEMM, LDS-staged A, fused alpha (log2-domain) -----
template <int WM, int WN, int K, int H, bool AF32>
__global__ __launch_bounds__(WM * WN * 64) void gemm_f16_fused(
    const void* __restrict__ Av, const _Float16* __restrict__ Wt,
    const float* __restrict__ a_s, const float* __restrict__ a_d,
    _Float16* __restrict__ hout, float* __restrict__ als,
    float* __restrict__ ald, int M, int Nn) {
    constexpr int BM = WM * 64;
    constexpr int T = WM * WN * 64;
    constexpr int CHUNKS = BM * 16;
    __shared__ f16x8 Atile[BM * 16];
    const _Float16* A16 = (const _Float16*)Av;
    const float* A32 = (const float*)Av;
    const int t = threadIdx.x;
    const int lane = t & 63;
    const int wv = t >> 6;
    const int wm = wv / WN, wn = wv % WN;
    const int m0 = blockIdx.x * BM;
    const int n0 = blockIdx.y * (WN * 64);
    const int l15 = lane & 15, lg = lane >> 4;

    f32x4 acc[4][4];
    const f32x4 zz = {0.f, 0.f, 0.f, 0.f};
#pragma unroll
    for (int mi = 0; mi < 4; ++mi)
#pragma unroll
        for (int ni = 0; ni < 4; ++ni) acc[mi][ni] = zz;

    for (int kc = 0; kc < K; kc += 128) {
        __syncthreads();
#pragma unroll
        for (int i = 0; i < CHUNKS / T; ++i) {
            const int c = i * T + t;
            const int row = c >> 4, cc = c & 15;
            const int gr = m0 + row;
            f16x8 v;
            if (gr < M) {
                if constexpr (AF32) {
                    float4 p = *(const float4*)(A32 + (size_t)gr * K + kc + cc * 8);
                    float4 q = *(const float4*)(A32 + (size_t)gr * K + kc + cc * 8 + 4);
                    v[0] = (_Float16)p.x; v[1] = (_Float16)p.y;
                    v[2] = (_Float16)p.z; v[3] = (_Float16)p.w;
                    v[4] = (_Float16)q.x; v[5] = (_Float16)q.y;
                    v[6] = (_Float16)q.z; v[7] = (_Float16)q.w;
                } else {
                    v = *(const f16x8*)(A16 + (size_t)gr * K + kc + cc * 8);
                }
            } else {
                v = f16x8_zero();
            }
            Atile[(row * 16 + cc) ^ (row & 7)] = v;
        }
        __syncthreads();
#pragma unroll
        for (int ks = 0; ks < 4; ++ks) {
            f16x8 af[4], bf[4];
#pragma unroll
            for (int mi = 0; mi < 4; ++mi) {
                const int row = wm * 64 + mi * 16 + l15;
                af[mi] = Atile[(row * 16 + ks * 4 + lg) ^ (row & 7)];
            }
#pragma unroll
            for (int ni = 0; ni < 4; ++ni) {
                const int col = n0 + wn * 64 + ni * 16 + l15;
                bf[ni] = *(const f16x8*)(Wt + (size_t)col * K + kc + ks * 32 + lg * 8);
            }
#pragma unroll
            for (int mi = 0; mi < 4; ++mi)
#pragma unroll
                for (int ni = 0; ni < 4; ++ni)
                    acc[mi][ni] = __builtin_amdgcn_mfma_f32_16x16x32_f16(
                        af[mi], bf[ni], acc[mi][ni], 0, 0, 0);
        }
    }
    const int head = (n0 + wn * 64) >> 6;
    float a4s[4], a4d[4];
#pragma unroll
    for (int ni = 0; ni < 4; ++ni) {
        a4s[ni] = a_s[head * 64 + ni * 16 + l15] * LOG2E;
        a4d[ni] = a_d[head * 64 + ni * 16 + l15] * LOG2E;
    }
#pragma unroll
    for (int mi = 0; mi < 4; ++mi)
#pragma unroll
        for (int j = 0; j < 4; ++j) {
            const int r = m0 + wm * 64 + mi * 16 + lg * 4 + j;
            if (r < M) {
                float s1 = 0.f, s2 = 0.f;
#pragma unroll
                for (int ni = 0; ni < 4; ++ni) {
                    const float v = acc[mi][ni][j];
                    s1 += v * a4s[ni];
                    s2 += v * a4d[ni];
                    hout[(size_t)r * Nn + n0 + wn * 64 + ni * 16 + l15] = (_Float16)v;
                }
#pragma unroll
                for (int o = 8; o; o >>= 1) {
                    s1 += __shfl_xor(s1, o);
                    s2 += __shfl_xor(s2, o);
                }
                if (l15 == 0) {
                    als[(size_t)r * H + head] = s1;
                    ald[(size_t)r * H + head] = s2;
                }
            }
        }
}

// ---------------- aggregation H=4: 2 nodes per wave ----------
// lane l: node = pair_base + (l>>5), q = l&31, channels q*8..q*8+7, head q>>3.
// Per edge: 1 LDS scalar w (broadcast), 1 f16x8 gather (16B), 8 fma_mix.
__global__ __launch_bounds__(256) void gat_agg_h4(
    const _Float16* __restrict__ hhf, const float4* __restrict__ als4,
    const float4* __restrict__ ald4, const int* __restrict__ csrsrc,
    const int* __restrict__ offv, const float* __restrict__ bias,
    _Float16* __restrict__ outh, int N) {
    __shared__ int sidAll[4][2][36];
    __shared__ float wTAll[4][2][4][36];   // bank-disjoint: verified
    const int wv = threadIdx.x >> 6;
    const int l = threadIdx.x & 63;
    const int half = l >> 5;
    const int q = l & 31;
    const int n = (blockIdx.x * 4 + wv) * 2 + half;
    if (n >= N) return;
    const int hh = q >> 3;
    int* sid = sidAll[wv][half];
    float* wrow = wTAll[wv][half][hh];            // this lane's head slice
    float (*wT)[36] = wTAll[wv][half];
    const int start = offv[n];
    const int deg = offv[n + 1] - start;
    const float4 ad = ald4[n];
    const float4 asf = als4[n];
    float4 ws4;
    ws4.x = fexp2(LRELU(asf.x + ad.x));
    ws4.y = fexp2(LRELU(asf.y + ad.y));
    ws4.z = fexp2(LRELU(asf.z + ad.z));
    ws4.w = fexp2(LRELU(asf.w + ad.w));
    float wself = ws4.x;
    wself = (hh == 1) ? ws4.y : wself;
    wself = (hh == 2) ? ws4.z : wself;
    wself = (hh == 3) ? ws4.w : wself;
    float accA[8], accB[8] = {};
    {
        const f16x8 hv = *(const f16x8*)(hhf + (size_t)n * 256 + q * 8);
#pragma unroll
        for (int c = 0; c < 8; ++c) accA[c] = (float)hv[c] * wself;
    }
    float dsum = wself;

    for (int base = 0; base < deg; base += 32) {
        const int nb = min(32, deg - base);
        int s = 0;
        float4 w4 = {0.f, 0.f, 0.f, 0.f};
        if (q < nb) {
            s = csrsrc[start + base + q];
            const float4 av = als4[s];
            w4.x = fexp2(LRELU(av.x + ad.x));
            w4.y = fexp2(LRELU(av.y + ad.y));
            w4.z = fexp2(LRELU(av.z + ad.z));
            w4.w = fexp2(LRELU(av.w + ad.w));
        }
        sid[q] = s;
        wT[0][q] = w4.x;
        wT[1][q] = w4.y;
        wT[2][q] = w4.z;
        wT[3][q] = w4.w;
        __threadfence_block();   // same-wave LDS write->read ordering
        int i = 0;
        for (; i + 1 < nb; i += 2) {
            const int sA = sid[i], sB = sid[i + 1];
            const float wA = wrow[i], wB = wrow[i + 1];
            const f16x8 hA = *(const f16x8*)(hhf + (size_t)sA * 256 + q * 8);
            const f16x8 hB = *(const f16x8*)(hhf + (size_t)sB * 256 + q * 8);
            dsum += wA + wB;
#pragma unroll
            for (int c = 0; c < 8; ++c) {
                accA[c] += (float)hA[c] * wA;
                accB[c] += (float)hB[c] * wB;
            }
        }
        if (i < nb) {
            const int sA = sid[i];
            const float wA = wrow[i];
            const f16x8 hA = *(const f16x8*)(hhf + (size_t)sA * 256 + q * 8);
            dsum += wA;
#pragma unroll
            for (int c = 0; c < 8; ++c) accA[c] += (float)hA[c] * wA;
        }
        __threadfence_block();   // reads done before next chunk's writes
    }
    const float inv = 1.f / (dsum + 1e-16f);
    const float4 bv0 = *(const float4*)(bias + q * 8);
    const float4 bv1 = *(const float4*)(bias + q * 8 + 4);
    float o8[8];
#pragma unroll
    for (int c = 0; c < 8; ++c) o8[c] = (accA[c] + accB[c]) * inv;
    o8[0] += bv0.x; o8[1] += bv0.y; o8[2] += bv0.z; o8[3] += bv0.w;
    o8[4] += bv1.x; o8[5] += bv1.y; o8[6] += bv1.z; o8[7] += bv1.w;
#pragma unroll
    for (int c = 0; c < 8; ++c)
        o8[c] = (o8[c] > 0.f) ? o8[c] : (__expf(o8[c]) - 1.f);   // ELU
    f16x8 st;
#pragma unroll
    for (int c = 0; c < 8; ++c) st[c] = (_Float16)o8[c];
    *(f16x8*)(outh + (size_t)n * 256 + q * 8) = st;
}

// H=1 (F=64) + ReLU + classifier + log_softmax; wave-parallel classifier.
__global__ __launch_bounds__(256) void gat_agg_h1_cls(
    const _Float16* __restrict__ hhf, const float* __restrict__ als,
    const float* __restrict__ ald, const int* __restrict__ csrsrc,
    const int* __restrict__ offv, const float* __restrict__ bias,
    const float* __restrict__ cW1, const float* __restrict__ cb1,
    const float* __restrict__ cW2, const float* __restrict__ cb2,
    float* __restrict__ outp, int N) {
    __shared__ float w1s[2048];   // cW1 [64][32]
    __shared__ float w2s[64];     // cW2 [32][2]
    __shared__ int sidAll[4][64];
    __shared__ float wAll[4][64];
    __shared__ float xsAll[4][64];
    for (int i = threadIdx.x; i < 2048; i += 256) w1s[i] = cW1[i];
    if (threadIdx.x < 64) w2s[threadIdx.x] = cW2[threadIdx.x];
    __syncthreads();   // uniform, once
    const int wv = threadIdx.x >> 6;
    const int t = threadIdx.x & 63;
    const int n = blockIdx.x * 4 + wv;
    if (n >= N) return;
    int* sid = sidAll[wv];
    float* wsh = wAll[wv];
    float* xs = xsAll[wv];
    const int start = offv[n];
    const int deg = offv[n + 1] - start;
    const float ad = ald[n];
    const float wself = fexp2(LRELU(als[n] + ad));
    float a0 = (float)hhf[(size_t)n * 64 + t] * wself;
    float a1 = 0.f, a2 = 0.f, a3 = 0.f;
    float wacc = (t == 0) ? wself : 0.f;

    for (int base = 0; base < deg; base += 64) {
        const int nb = min(64, deg - base);
        int s = 0;
        float w = 0.f;
        if (t < nb) {
            s = csrsrc[start + base + t];
            w = fexp2(LRELU(als[s] + ad));
            wacc += w;
        }
        sid[t] = s;
        wsh[t] = w;
        __threadfence_block();
        int i = 0;
        for (; i + 3 < nb; i += 4) {
            const int4 ss = *(const int4*)&sid[i];
            const float4 ww = *(const float4*)&wsh[i];
            a0 += (float)hhf[(size_t)ss.x * 64 + t] * ww.x;
            a1 += (float)hhf[(size_t)ss.y * 64 + t] * ww.y;
            a2 += (float)hhf[(size_t)ss.z * 64 + t] * ww.z;
            a3 += (float)hhf[(size_t)ss.w * 64 + t] * ww.w;
        }
        for (; i < nb; ++i) {
            a0 += (float)hhf[(size_t)sid[i] * 64 + t] * wsh[i];
        }
        __threadfence_block();
    }
#pragma unroll
    for (int o = 32; o; o >>= 1) wacc += __shfl_xor(wacc, o);
    const float val = fmaxf((a0 + a1 + a2 + a3) / (wacc + 1e-16f) + bias[t], 0.f);
    // ---- classifier, wave-parallel ----
    xs[t] = val;
    __threadfence_block();
    const int j = t & 31;
    const int half = t >> 5;
    float s1 = 0.f;
#pragma unroll
    for (int cc = 0; cc < 32; ++cc) {
        const int c = half * 32 + cc;
        s1 += xs[c] * w1s[c * 32 + j];
    }
    s1 += __shfl_xor(s1, 32);
    const float hid = fmaxf(s1 + cb1[j], 0.f);
    const int k = t & 1, jj = t >> 1;
    const float hjj = __shfl(hid, jj);
    float s2 = hjj * w2s[jj * 2 + k];
#pragma unroll
    for (int o = 2; o < 64; o <<= 1) s2 += __shfl_xor(s2, o);
    s2 += cb2[k];
    const float a = __shfl(s2, 0);
    const float b = __shfl(s2, 1);
    const float mm = fmaxf(a, b);
    const float lse = mm + logf(__expf(a - mm) + __expf(b - mm));
    if (t < 2) outp[(size_t)n * 2 + t] = s2 - lse;
}

extern "C" void kernel_launch(void* const* d_in, const int* in_sizes, int n_in,
                              void* d_out, int out_size, void* d_ws, size_t ws_size,
                              hipStream_t stream) {
    const float* x   = (const float*)d_in[0];
    const int*   ei  = (const int*)d_in[1];
    const float* W1  = (const float*)d_in[2];
    const float* a1s = (const float*)d_in[3];
    const float* a1d = (const float*)d_in[4];
    const float* b1  = (const float*)d_in[5];
    const float* W2  = (const float*)d_in[6];
    const float* a2s = (const float*)d_in[7];
    const float* a2d = (const float*)d_in[8];
    const float* b2  = (const float*)d_in[9];
    const float* W3  = (const float*)d_in[10];
    const float* a3s = (const float*)d_in[11];
    const float* a3d = (const float*)d_in[12];
    const float* b3  = (const float*)d_in[13];
    const float* cW1 = (const float*)d_in[14];
    const float* cb1 = (const float*)d_in[15];
    const float* cW2 = (const float*)d_in[16];
    const float* cb2 = (const float*)d_in[17];

    const int N = in_sizes[0] / 128;   // 50000
    const int E = in_sizes[1] / 2;     // 500000
    const int* srcv = ei;
    const int* dstv = ei + E;

    // workspace layout, all segments 16B-aligned
    char* p = (char*)d_ws;
    _Float16* slotA = (_Float16*)p; p += (size_t)N * 256 * 2;   // h1h / h2h / h3h
    _Float16* slotB = (_Float16*)p; p += (size_t)N * 256 * 2;   // a1h / a2h
    float* als = (float*)p; p += (size_t)N * 4 * 4;
    float* ald = (float*)p; p += (size_t)N * 4 * 4;
    int* cnt = (int*)p; p += (size_t)N * 4;
    int* offv = (int*)p; p += (size_t)(N + 4) * 4;
    int* csr = (int*)p; p += (size_t)E * 4;
    _Float16* Wt1 = (_Float16*)p; p += (size_t)128 * 256 * 2;
    _Float16* Wt2 = (_Float16*)p; p += (size_t)256 * 256 * 2;
    _Float16* Wt3 = (_Float16*)p; p += (size_t)256 * 64 * 2;
    int* bsum = (int*)p;

    // weight transposes (one dispatch)
    prep_w_all<<<(128 * 256 + 256 * 256 + 256 * 64 + 255) / 256, 256, 0, stream>>>(
        W1, W2, W3, Wt1, Wt2, Wt3);

    // CSR by destination
    const int NB = (N + 1023) / 1024;   // 49
    hipMemsetAsync(cnt, 0, (size_t)N * sizeof(int), stream);
    hist_kernel<<<(E + 255) / 256, 256, 0, stream>>>(dstv, cnt, E);
    scan_blk<<<NB, 256, 0, stream>>>(cnt, offv, bsum, N);
    scan_top<<<1, 64, 0, stream>>>(bsum, offv, NB, N);
    scan_add<<<NB, 256, 0, stream>>>(offv, bsum, N);
    hipMemsetAsync(cnt, 0, (size_t)N * sizeof(int), stream);
    fill_kernel<<<(E + 255) / 256, 256, 0, stream>>>(dstv, srcv, offv, cnt, csr, E);

    const int MB128 = (N + 127) / 128;   // 391
    const int MB256 = (N + 255) / 256;   // 196
    const int AGG8 = (N + 7) / 8;        // 6250  (8 nodes per 256-thr block)
    const int AGG4 = (N + 3) / 4;        // 12500

    // ---- layer 1 (128 -> 256, H=4, ELU); A = x fp32, converted in staging ----
    gemm_f16_fused<2, 4, 128, 4, true><<<dim3(MB128, 1), 512, 0, stream>>>(
        x, Wt1, a1s, a1d, slotA, als, ald, N, 256);
    gat_agg_h4<<<AGG8, 256, 0, stream>>>(slotA, (const float4*)als,
                                         (const float4*)ald, csr, offv, b1,
                                         slotB, N);

    // ---- layer 2 (256 -> 256, H=4, ELU) ----
    gemm_f16_fused<2, 4, 256, 4, false><<<dim3(MB128, 1), 512, 0, stream>>>(
        slotB, Wt2, a2s, a2d, slotA, als, ald, N, 256);
    gat_agg_h4<<<AGG8, 256, 0, stream>>>(slotA, (const float4*)als,
                                         (const float4*)ald, csr, offv, b2,
                                         slotB, N);

    // ---- layer 3 (256 -> 64, H=1) + agg + classifier + log_softmax ----
    gemm_f16_fused<4, 1, 256, 1, false><<<dim3(MB256, 1), 256, 0, stream>>>(
        slotB, Wt3, a3s, a3d, slotA, als, ald, N, 64);
    gat_agg_h1_cls<<<AGG4, 256, 0, stream>>>(slotA, als, ald, csr,
                                             offv, b3, cW1, cb1, cW2, cb2,
                                             (float*)d_out, N);
}